// Round 3
// baseline (339.181 us; speedup 1.0000x reference)
//
#include <hip/hip_runtime.h>

typedef unsigned short u16;
typedef unsigned int u32;
typedef short bf16x8 __attribute__((ext_vector_type(8)));
typedef float f32x4 __attribute__((ext_vector_type(4)));

#define LQ_ 21760
#define LIN_ 21760
#define CDIM 256
#define MROWS (2 * LQ_)  // 43520

__device__ __forceinline__ u16 f2bf(float f) {
  u32 u;
  __builtin_memcpy(&u, &f, 4);
  u32 r = (u + 0x7fffu + ((u >> 16) & 1u)) >> 16;
  return (u16)r;
}
__device__ __forceinline__ u32 pack_bf16_rne(float a, float b) {
  return (u32)f2bf(a) | ((u32)f2bf(b) << 16);
}
__device__ __forceinline__ float bflo(u32 u) {
  u32 v = u << 16;
  float f;
  __builtin_memcpy(&f, &v, 4);
  return f;
}
__device__ __forceinline__ float bfhi(u32 u) {
  u32 v = u & 0xffff0000u;
  float f;
  __builtin_memcpy(&f, &v, 4);
  return f;
}

// ---------- weight pre-conversion to bf16 fragment-chunk layout (B side only) ----------
// chunkIdx = ks*(N/4) + (n>>4)*4 + ((k>>3)&3); element (n&15)*8 + (k&7).
__device__ __forceinline__ void conv_one(const float* W0, const float* W1, u16* Wf,
                                         int N, int split, int blk, int t) {
  const int tid = blk * 256 + t;
  if (tid >= N * 32) return;
  const int n = tid >> 5, kcg = tid & 31;
  float w[8];
#pragma unroll
  for (int j = 0; j < 8; ++j) {
    const int k = kcg * 8 + j;
    w[j] = (n < split) ? W0[(size_t)k * split + n]
                       : W1[(size_t)k * (N - split) + (n - split)];
  }
  uint4 pk;
  pk.x = pack_bf16_rne(w[0], w[1]);
  pk.y = pack_bf16_rne(w[2], w[3]);
  pk.z = pack_bf16_rne(w[4], w[5]);
  pk.w = pack_bf16_rne(w[6], w[7]);
  const int ks = kcg >> 2, kcr = kcg & 3, c = n >> 4;
  const int chunk = ks * (N / 4) + c * 4 + kcr;
  *(uint4*)(Wf + (size_t)chunk * 128 + (n & 15) * 8) = pk;
}

// ---------- fused pre-conversion: weights (blocks 0..113) + ROW-MAJOR activation cast --
// Activations: Qf/If are plain row-major bf16 casts of query/inflat.
// Thread j: read 32 contiguous bytes (2 float4), write 16 contiguous bytes (uint4).
// Wave = 2 KB contiguous read, 1 KB contiguous write -> fully coalesced both sides.
__global__ __launch_bounds__(256) void conv_fused(
    const float* __restrict__ Wv, const float* __restrict__ Wof,
    const float* __restrict__ Wa, const float* __restrict__ Wo,
    const float* __restrict__ bof, const float* __restrict__ ba,
    u16* __restrict__ WfV, u16* __restrict__ WfC, u16* __restrict__ WfO,
    float* __restrict__ bcat, const float* __restrict__ Aq,
    const float* __restrict__ Ai, u16* __restrict__ Qf, u16* __restrict__ If) {
  const int b = blockIdx.x, t = threadIdx.x;
  if (b < 32) {
    conv_one(Wv, Wv, WfV, 256, 256, b, t);
    return;
  }
  if (b < 80) {
    conv_one(Wof, Wa, WfC, 384, 256, b - 32, t);
    return;
  }
  if (b < 112) {
    conv_one(Wo, Wo, WfO, 256, 256, b - 80, t);
    return;
  }
  if (b < 114) {
    const int i = (b - 112) * 256 + t;
    if (i < 384) bcat[i] = (i < 256) ? bof[i] : ba[i - 256];
    return;
  }
  const int i = (b - 114) * 256 + t;
  const int n4 = MROWS * 32;
  const float* src;
  u16* dst;
  int j;
  if (i < n4) {
    src = Aq;
    dst = Qf;
    j = i;
  } else {
    src = Ai;
    dst = If;
    j = i - n4;
  }
  const float4 f0 = *(const float4*)(src + (size_t)j * 8);
  const float4 f1 = *(const float4*)(src + (size_t)j * 8 + 4);
  uint4 pk;
  pk.x = pack_bf16_rne(f0.x, f0.y);
  pk.y = pack_bf16_rne(f0.z, f0.w);
  pk.z = pack_bf16_rne(f1.x, f1.y);
  pk.w = pack_bf16_rne(f1.z, f1.w);
  *(uint4*)(dst + (size_t)j * 8) = pk;
}

// ---------- register-direct GEMMs: row-major A, on-demand af loads, 128-VGPR budget ----
// af[ks][r] frag == A[rb*128+wr*64+r*16+fr][ks*32+fq*8 ..+7] (row-major 16B chunk).
// Loading af inside the ks loop (re-read per cb, L2-hot 64KB panel) keeps live regs
// ~110 (acc 64 + af 16 + bf 16) -> 4 waves/SIMD vs 2 with the 128-reg A panel.
// Opaque zero offset per cb defeats cross-cb CSE of the af loads.
__global__ __launch_bounds__(256, 4) void gemm_vq(
    const u16* __restrict__ If, const u16* __restrict__ WfV,
    const float* __restrict__ bv, u16* __restrict__ outV,
    const u16* __restrict__ Qf, const u16* __restrict__ WfC,
    const float* __restrict__ bcat, float* __restrict__ outO,
    float* __restrict__ outA) {
  const int t = threadIdx.x, l = t & 63, wv = t >> 6;
  const int wr = wv >> 1, wc = wv & 1;
  const int fq = l >> 4, fr = l & 15;

  if (blockIdx.x < 340) {
    const int rb = blockIdx.x;
    const u16* ab = If + ((size_t)(rb * 128 + wr * 64 + fr)) * 256 + fq * 8;
#pragma unroll
    for (int cb = 0; cb < 2; ++cb) {
      int zz = 0;
      asm volatile("" : "+v"(zz));
      const u16* abx = ab + zz;
      f32x4 acc[4][4];
#pragma unroll
      for (int r = 0; r < 4; ++r)
#pragma unroll
        for (int c = 0; c < 4; ++c) acc[r][c] = f32x4{0.f, 0.f, 0.f, 0.f};
      const u16* bb = WfV + ((size_t)(cb * 8 + wc * 4) * 4 + fq) * 128 + fr * 8;
#pragma unroll
      for (int ks = 0; ks < 8; ++ks) {
        bf16x8 af[4];
#pragma unroll
        for (int r = 0; r < 4; ++r)
          af[r] = *(const bf16x8*)(abx + (size_t)r * 4096 + ks * 32);
        bf16x8 bf[4];
#pragma unroll
        for (int c = 0; c < 4; ++c) bf[c] = *(const bf16x8*)(bb + ks * 8192 + c * 512);
#pragma unroll
        for (int c = 0; c < 4; ++c)
#pragma unroll
          for (int r = 0; r < 4; ++r)
            acc[r][c] = __builtin_amdgcn_mfma_f32_16x16x32_bf16(af[r], bf[c],
                                                                acc[r][c], 0, 0, 0);
      }
      const int rq = fq * 4;
#pragma unroll
      for (int c = 0; c < 4; ++c) {
        const int col = cb * 128 + wc * 64 + c * 16 + fr;
        const float bz = bv[col];
#pragma unroll
        for (int r = 0; r < 4; ++r) {
          const int row0 = rb * 128 + wr * 64 + r * 16 + rq;
#pragma unroll
          for (int g = 0; g < 4; ++g)
            outV[(size_t)(row0 + g) * 256 + col] = f2bf(acc[r][c][g] + bz);
        }
      }
    }
  } else {
    const int rb = blockIdx.x - 340;
    const u16* ab = Qf + ((size_t)(rb * 128 + wr * 64 + fr)) * 256 + fq * 8;
#pragma unroll
    for (int cb = 0; cb < 3; ++cb) {
      int zz = 0;
      asm volatile("" : "+v"(zz));
      const u16* abx = ab + zz;
      f32x4 acc[4][4];
#pragma unroll
      for (int r = 0; r < 4; ++r)
#pragma unroll
        for (int c = 0; c < 4; ++c) acc[r][c] = f32x4{0.f, 0.f, 0.f, 0.f};
      const u16* bb = WfC + ((size_t)(cb * 8 + wc * 4) * 4 + fq) * 128 + fr * 8;
#pragma unroll
      for (int ks = 0; ks < 8; ++ks) {
        bf16x8 af[4];
#pragma unroll
        for (int r = 0; r < 4; ++r)
          af[r] = *(const bf16x8*)(abx + (size_t)r * 4096 + ks * 32);
        bf16x8 bf[4];
#pragma unroll
        for (int c = 0; c < 4; ++c) bf[c] = *(const bf16x8*)(bb + ks * 12288 + c * 512);
#pragma unroll
        for (int c = 0; c < 4; ++c)
#pragma unroll
          for (int r = 0; r < 4; ++r)
            acc[r][c] = __builtin_amdgcn_mfma_f32_16x16x32_bf16(af[r], bf[c],
                                                                acc[r][c], 0, 0, 0);
      }
      const int rq = fq * 4;
#pragma unroll
      for (int c = 0; c < 4; ++c) {
        const int col = cb * 128 + wc * 64 + c * 16 + fr;
        const float bz = bcat[col];
#pragma unroll
        for (int r = 0; r < 4; ++r) {
          const int row0 = rb * 128 + wr * 64 + r * 16 + rq;
#pragma unroll
          for (int g = 0; g < 4; ++g) {
            const float v = acc[r][c][g] + bz;
            if (col < 256)
              outO[(size_t)(row0 + g) * 256 + col] = v;
            else
              outA[(size_t)(row0 + g) * 128 + (col - 256)] = v;
          }
        }
      }
    }
  }
}

// ---------- GEMM 3: out = samp(row-major bf16) @ WfO + bo -> f32 ----------
__global__ __launch_bounds__(256, 4) void gemm_out(
    const u16* __restrict__ A, const u16* __restrict__ Wf,
    const float* __restrict__ bias, float* __restrict__ out) {
  const int rb = blockIdx.x;
  const int t = threadIdx.x, l = t & 63, wv = t >> 6;
  const int wr = wv >> 1, wc = wv & 1;
  const int fq = l >> 4, fr = l & 15;
  const u16* ab = A + ((size_t)rb * 128 + wr * 64 + fr) * 256 + fq * 8;
#pragma unroll
  for (int cb = 0; cb < 2; ++cb) {
    int zz = 0;
    asm volatile("" : "+v"(zz));
    const u16* abx = ab + zz;
    f32x4 acc[4][4];
#pragma unroll
    for (int r = 0; r < 4; ++r)
#pragma unroll
      for (int c = 0; c < 4; ++c) acc[r][c] = f32x4{0.f, 0.f, 0.f, 0.f};
    const u16* bb = Wf + ((size_t)(cb * 8 + wc * 4) * 4 + fq) * 128 + fr * 8;
#pragma unroll
    for (int ks = 0; ks < 8; ++ks) {
      bf16x8 af[4];
#pragma unroll
      for (int r = 0; r < 4; ++r)
        af[r] = *(const bf16x8*)(abx + (size_t)r * 4096 + ks * 32);
      bf16x8 bf[4];
#pragma unroll
      for (int c = 0; c < 4; ++c) bf[c] = *(const bf16x8*)(bb + ks * 8192 + c * 512);
#pragma unroll
      for (int c = 0; c < 4; ++c)
#pragma unroll
        for (int r = 0; r < 4; ++r)
          acc[r][c] = __builtin_amdgcn_mfma_f32_16x16x32_bf16(af[r], bf[c],
                                                              acc[r][c], 0, 0, 0);
    }
    const int rq = fq * 4;
#pragma unroll
    for (int c = 0; c < 4; ++c) {
      const int col = cb * 128 + wc * 64 + c * 16 + fr;
      const float bz = bias[col];
#pragma unroll
      for (int r = 0; r < 4; ++r) {
        const int row0 = rb * 128 + wr * 64 + r * 16 + rq;
#pragma unroll
        for (int g = 0; g < 4; ++g)
          out[(size_t)(row0 + g) * 256 + col] = acc[r][c][g] + bz;
      }
    }
  }
}

// ---------- sampler: round-2 config (91 us, best known) ----------
__global__ __launch_bounds__(256, 4) void msda_sample5(
    const u16* __restrict__ value, const float* __restrict__ off,
    const float* __restrict__ attnl, const float* __restrict__ refp,
    u16* __restrict__ out) {
  __shared__ float s_aw[64 * 17];     // 4352 B
  __shared__ ushort4 s_idx[16 * 64];  // 8192 B (row indices < 21760 fit u16)
  __shared__ float4 s_w[16 * 64];     // 16384 B
  const int t = threadIdx.x;
  const int bq0 = blockIdx.x * 8;

  if (t < 64) {
    const float* lg = attnl + (size_t)(bq0 + (t >> 3)) * 128 + (t & 7) * 16;
    float e[16];
    float m = -1e30f;
#pragma unroll
    for (int i = 0; i < 16; ++i) {
      e[i] = lg[i];
      m = fmaxf(m, e[i]);
    }
    float s = 0.f;
#pragma unroll
    for (int i = 0; i < 16; ++i) {
      e[i] = __expf(e[i] - m);
      s += e[i];
    }
    const float inv = 1.f / s;
#pragma unroll
    for (int i = 0; i < 16; ++i) s_aw[t * 17 + i] = e[i] * inv;
  }
  __syncthreads();

#pragma unroll
  for (int rr = 0; rr < 4; ++rr) {
    const int id = t + rr * 256;
    const int qh = id & 63, lp = id >> 6;
    const int q = qh >> 3, h = qh & 7, lv = lp >> 2, p = lp & 3;
    const int bq = bq0 + q;
    const int Wl = 128 >> lv;
    const int st = (lv == 0) ? 0 : (lv == 1) ? 16384 : (lv == 2) ? 20480 : 21504;
    const float ox = off[(size_t)bq * 256 + ((h * 4 + lv) * 4 + p) * 2];
    const float oy = off[(size_t)bq * 256 + ((h * 4 + lv) * 4 + p) * 2 + 1];
    const float rx = refp[(size_t)bq * 8 + lv * 2];
    const float ry = refp[(size_t)bq * 8 + lv * 2 + 1];
    const float aw = s_aw[qh * 17 + lp];
    const float x = rx * (float)Wl + ox - 0.5f;
    const float y = ry * (float)Wl + oy - 0.5f;
    const float xf = floorf(x), yf = floorf(y);
    const int x0 = (int)xf, y0 = (int)yf;
    const float lw = x - xf, lh = y - yf;
    const float hw = 1.f - lw, hh = 1.f - lh;
    const int ixs[4] = {x0, x0 + 1, x0, x0 + 1};
    const int iys[4] = {y0, y0, y0 + 1, y0 + 1};
    const float wts[4] = {hw * hh, lw * hh, hw * lh, lw * lh};
    u32 rows[4];
    float ws4[4];
#pragma unroll
    for (int c = 0; c < 4; ++c) {
      const int ix = ixs[c], iy = iys[c];
      const bool valid = (ix >= 0) & (ix < Wl) & (iy >= 0) & (iy < Wl);
      int idx = iy * Wl + ix;
      idx = max(0, min(idx, Wl * Wl - 1));
      rows[c] = (u32)(st + idx);
      ws4[c] = valid ? (wts[c] * aw) : 0.f;
    }
    ushort4 iv;
    iv.x = (u16)rows[0];
    iv.y = (u16)rows[1];
    iv.z = (u16)rows[2];
    iv.w = (u16)rows[3];
    s_idx[lp * 64 + qh] = iv;
    s_w[lp * 64 + qh] = make_float4(ws4[0], ws4[1], ws4[2], ws4[3]);
  }
  __syncthreads();

  const int q = t >> 5, h = (t >> 2) & 7, dg = t & 3;
  const int qh = q * 8 + h;
  const int bq = bq0 + q;
  const u16* vp = value + (size_t)((bq >= LQ_) ? LIN_ : 0) * CDIM + h * 32 + dg * 8;
  float a0 = 0.f, a1 = 0.f, a2 = 0.f, a3 = 0.f;
  float a4 = 0.f, a5 = 0.f, a6 = 0.f, a7 = 0.f;
#pragma unroll
  for (int lp = 0; lp < 16; ++lp) {
    const ushort4 iv = s_idx[lp * 64 + qh];
    const float4 wv = s_w[lp * 64 + qh];
    const u32 rows[4] = {iv.x, iv.y, iv.z, iv.w};
    const float ww[4] = {wv.x, wv.y, wv.z, wv.w};
#pragma unroll
    for (int c = 0; c < 4; ++c) {
      const uint4 d = *(const uint4*)(vp + (size_t)rows[c] * CDIM);
      const float w = ww[c];
      a0 += w * bflo(d.x);
      a1 += w * bfhi(d.x);
      a2 += w * bflo(d.y);
      a3 += w * bfhi(d.y);
      a4 += w * bflo(d.z);
      a5 += w * bfhi(d.z);
      a6 += w * bflo(d.w);
      a7 += w * bfhi(d.w);
    }
  }
  uint4 o;
  o.x = pack_bf16_rne(a0, a1);
  o.y = pack_bf16_rne(a2, a3);
  o.z = pack_bf16_rne(a4, a5);
  o.w = pack_bf16_rne(a6, a7);
  *(uint4*)(out + (size_t)bq * CDIM + h * 32 + dg * 8) = o;
}

extern "C" void kernel_launch(void* const* d_in, const int* in_sizes, int n_in,
                              void* d_out, int out_size, void* d_ws, size_t ws_size,
                              hipStream_t stream) {
  const float* query = (const float*)d_in[0];
  const float* refp = (const float*)d_in[1];
  const float* inflat = (const float*)d_in[2];
  const float* Wv = (const float*)d_in[3];
  const float* bv = (const float*)d_in[4];
  const float* Wof = (const float*)d_in[5];
  const float* bof = (const float*)d_in[6];
  const float* Wa = (const float*)d_in[7];
  const float* ba = (const float*)d_in[8];
  const float* Wo = (const float*)d_in[9];
  const float* bo = (const float*)d_in[10];
  float* out = (float*)d_out;

  const size_t M = MROWS;

  u16* If = (u16*)d_ws;                          // M*256 bf16 row-major (reused as samp)
  u16* Qf = If + M * 256;                        // M*256 bf16 row-major
  u16* ws_value = Qf + M * 256;                  // M*256 bf16 row-major
  float* ws_off = (float*)(ws_value + M * 256);  // M*256 f32
  float* ws_attn = ws_off + M * 256;             // M*128 f32
  u16* WfV = (u16*)(ws_attn + M * 128);          // 256*256 bf16
  u16* WfC = WfV + 256 * 256;                    // 256*384 bf16
  u16* WfO = WfC + 384 * 256;                    // 256*256 bf16
  float* bcat = (float*)(WfO + 256 * 256);       // 384 f32
  u16* ws_samp = If;                             // alias: If dead after gemm_vq

  conv_fused<<<dim3(10994), dim3(256), 0, stream>>>(Wv, Wof, Wa, Wo, bof, ba, WfV, WfC,
                                                    WfO, bcat, query, inflat, Qf, If);
  gemm_vq<<<dim3(680), dim3(256), 0, stream>>>(If, WfV, bv, ws_value, Qf, WfC, bcat,
                                               ws_off, ws_attn);
  msda_sample5<<<dim3(5440), dim3(256), 0, stream>>>(ws_value, ws_off, ws_attn, refp,
                                                     ws_samp);
  gemm_out<<<dim3(340), dim3(256), 0, stream>>>(ws_samp, WfO, bo, out);
}

// Round 4
// 286.858 us; speedup vs baseline: 1.1824x; 1.1824x over previous
//
#include <hip/hip_runtime.h>

typedef unsigned short u16;
typedef unsigned int u32;
typedef short bf16x8 __attribute__((ext_vector_type(8)));
typedef float f32x4 __attribute__((ext_vector_type(4)));

#define LQ_ 21760
#define LIN_ 21760
#define CDIM 256
#define MROWS (2 * LQ_)  // 43520

__device__ __forceinline__ u16 f2bf(float f) {
  u32 u;
  __builtin_memcpy(&u, &f, 4);
  u32 r = (u + 0x7fffu + ((u >> 16) & 1u)) >> 16;
  return (u16)r;
}
__device__ __forceinline__ u32 pack_bf16_rne(float a, float b) {
  return (u32)f2bf(a) | ((u32)f2bf(b) << 16);
}
__device__ __forceinline__ float bflo(u32 u) {
  u32 v = u << 16;
  float f;
  __builtin_memcpy(&f, &v, 4);
  return f;
}
__device__ __forceinline__ float bfhi(u32 u) {
  u32 v = u & 0xffff0000u;
  float f;
  __builtin_memcpy(&f, &v, 4);
  return f;
}

// ---------- weight pre-conversion to bf16 fragment-chunk layout (B side) ----------
// chunkIdx = ks*(N/4) + (n>>4)*4 + ((k>>3)&3); element (n&15)*8 + (k&7).
__device__ __forceinline__ void conv_one(const float* W0, const float* W1, u16* Wf,
                                         int N, int split, int blk, int t) {
  const int tid = blk * 256 + t;
  if (tid >= N * 32) return;
  const int n = tid >> 5, kcg = tid & 31;
  float w[8];
#pragma unroll
  for (int j = 0; j < 8; ++j) {
    const int k = kcg * 8 + j;
    w[j] = (n < split) ? W0[(size_t)k * split + n]
                       : W1[(size_t)k * (N - split) + (n - split)];
  }
  uint4 pk;
  pk.x = pack_bf16_rne(w[0], w[1]);
  pk.y = pack_bf16_rne(w[2], w[3]);
  pk.z = pack_bf16_rne(w[4], w[5]);
  pk.w = pack_bf16_rne(w[6], w[7]);
  const int ks = kcg >> 2, kcr = kcg & 3, c = n >> 4;
  const int chunk = ks * (N / 4) + c * 4 + kcr;
  *(uint4*)(Wf + (size_t)chunk * 128 + (n & 15) * 8) = pk;
}

// ---------- weights-only pre-conversion (A staging moved into the GEMMs) ----------
__global__ __launch_bounds__(256) void conv_w(
    const float* __restrict__ Wv, const float* __restrict__ Wof,
    const float* __restrict__ Wa, const float* __restrict__ Wo,
    const float* __restrict__ bof, const float* __restrict__ ba,
    u16* __restrict__ WfV, u16* __restrict__ WfC, u16* __restrict__ WfO,
    float* __restrict__ bcat) {
  const int b = blockIdx.x, t = threadIdx.x;
  if (b < 32) {
    conv_one(Wv, Wv, WfV, 256, 256, b, t);
    return;
  }
  if (b < 80) {
    conv_one(Wof, Wa, WfC, 384, 256, b - 32, t);
    return;
  }
  if (b < 112) {
    conv_one(Wo, Wo, WfO, 256, 256, b - 80, t);
    return;
  }
  const int i = (b - 112) * 256 + t;
  if (i < 384) bcat[i] = (i < 256) ? bof[i] : ba[i - 256];
}

// ---------- LDS A-panel helpers ----------
// LDS layout: 128 rows x 256 bf16, elem-col XOR-swizzled by ((row&7)<<3) in 8-elem
// (16 B) granules. Staging ds_write and frag ds_read both uniform 2 lanes/bank (free).
__device__ __forceinline__ void stage_a_f32(u16* s_a, const float* __restrict__ ga,
                                            int t) {
#pragma unroll
  for (int it = 0; it < 16; ++it) {
    const int idx = it * 256 + t;
    const int row = idx >> 5, cc = idx & 31;
    const float4 f0 = *(const float4*)(ga + (size_t)row * 256 + cc * 8);
    const float4 f1 = *(const float4*)(ga + (size_t)row * 256 + cc * 8 + 4);
    uint4 pk;
    pk.x = pack_bf16_rne(f0.x, f0.y);
    pk.y = pack_bf16_rne(f0.z, f0.w);
    pk.z = pack_bf16_rne(f1.x, f1.y);
    pk.w = pack_bf16_rne(f1.z, f1.w);
    *(uint4*)(s_a + row * 256 + ((cc * 8) ^ ((row & 7) << 3))) = pk;
  }
}
__device__ __forceinline__ void stage_a_bf16(u16* s_a, const u16* __restrict__ ga,
                                             int t) {
#pragma unroll
  for (int it = 0; it < 16; ++it) {
    const int idx = it * 256 + t;
    const int row = idx >> 5, cc = idx & 31;
    const uint4 pk = *(const uint4*)(ga + (size_t)row * 256 + cc * 8);
    *(uint4*)(s_a + row * 256 + ((cc * 8) ^ ((row & 7) << 3))) = pk;
  }
}

// ---------- GEMM 1+2: A staged f32->bf16 in LDS, round-0 MFMA loop ----------
// blocks [0,340): value = inflat @ WfV + bv (bf16 out, N=256, 2 cb)
// blocks [340,680): [off|attn] = query @ WfC + bcat (f32 split, N=384, 3 cb)
__global__ __launch_bounds__(256) void gemm_vq(
    const float* __restrict__ Ai, const u16* __restrict__ WfV,
    const float* __restrict__ bv, u16* __restrict__ outV,
    const float* __restrict__ Aq, const u16* __restrict__ WfC,
    const float* __restrict__ bcat, float* __restrict__ outO,
    float* __restrict__ outA) {
  __shared__ u16 s_a[128 * 256];  // 64 KB
  const int t = threadIdx.x, l = t & 63, wv = t >> 6;
  const int wr = wv >> 1, wc = wv & 1;
  const int fq = l >> 4, fr = l & 15;
  const int swz = (fr & 7) << 3;

  if (blockIdx.x < 340) {
    const int rb = blockIdx.x;
    stage_a_f32(s_a, Ai + (size_t)rb * 128 * 256, t);
    __syncthreads();
#pragma unroll
    for (int cb = 0; cb < 2; ++cb) {
      f32x4 acc[4][4];
#pragma unroll
      for (int r = 0; r < 4; ++r)
#pragma unroll
        for (int c = 0; c < 4; ++c) acc[r][c] = f32x4{0.f, 0.f, 0.f, 0.f};
      const u16* bb = WfV + ((size_t)(cb * 8 + wc * 4) * 4 + fq) * 128 + fr * 8;
#pragma unroll
      for (int ks = 0; ks < 8; ++ks) {
        bf16x8 af[4];
#pragma unroll
        for (int r = 0; r < 4; ++r) {
          const int row = wr * 64 + r * 16 + fr;
          af[r] = *(const bf16x8*)(s_a + row * 256 + ((ks * 32 + fq * 8) ^ swz));
        }
        bf16x8 bf[4];
#pragma unroll
        for (int c = 0; c < 4; ++c) bf[c] = *(const bf16x8*)(bb + ks * 8192 + c * 512);
#pragma unroll
        for (int c = 0; c < 4; ++c)
#pragma unroll
          for (int r = 0; r < 4; ++r)
            acc[r][c] = __builtin_amdgcn_mfma_f32_16x16x32_bf16(af[r], bf[c],
                                                                acc[r][c], 0, 0, 0);
      }
      const int rq = fq * 4;
#pragma unroll
      for (int c = 0; c < 4; ++c) {
        const int col = cb * 128 + wc * 64 + c * 16 + fr;
        const float bz = bv[col];
#pragma unroll
        for (int r = 0; r < 4; ++r) {
          const int row0 = rb * 128 + wr * 64 + r * 16 + rq;
#pragma unroll
          for (int g = 0; g < 4; ++g)
            outV[(size_t)(row0 + g) * 256 + col] = f2bf(acc[r][c][g] + bz);
        }
      }
    }
  } else {
    const int rb = blockIdx.x - 340;
    stage_a_f32(s_a, Aq + (size_t)rb * 128 * 256, t);
    __syncthreads();
#pragma unroll
    for (int cb = 0; cb < 3; ++cb) {
      f32x4 acc[4][4];
#pragma unroll
      for (int r = 0; r < 4; ++r)
#pragma unroll
        for (int c = 0; c < 4; ++c) acc[r][c] = f32x4{0.f, 0.f, 0.f, 0.f};
      const u16* bb = WfC + ((size_t)(cb * 8 + wc * 4) * 4 + fq) * 128 + fr * 8;
#pragma unroll
      for (int ks = 0; ks < 8; ++ks) {
        bf16x8 af[4];
#pragma unroll
        for (int r = 0; r < 4; ++r) {
          const int row = wr * 64 + r * 16 + fr;
          af[r] = *(const bf16x8*)(s_a + row * 256 + ((ks * 32 + fq * 8) ^ swz));
        }
        bf16x8 bf[4];
#pragma unroll
        for (int c = 0; c < 4; ++c) bf[c] = *(const bf16x8*)(bb + ks * 12288 + c * 512);
#pragma unroll
        for (int c = 0; c < 4; ++c)
#pragma unroll
          for (int r = 0; r < 4; ++r)
            acc[r][c] = __builtin_amdgcn_mfma_f32_16x16x32_bf16(af[r], bf[c],
                                                                acc[r][c], 0, 0, 0);
      }
      const int rq = fq * 4;
#pragma unroll
      for (int c = 0; c < 4; ++c) {
        const int col = cb * 128 + wc * 64 + c * 16 + fr;
        const float bz = bcat[col];
#pragma unroll
        for (int r = 0; r < 4; ++r) {
          const int row0 = rb * 128 + wr * 64 + r * 16 + rq;
#pragma unroll
          for (int g = 0; g < 4; ++g) {
            const float v = acc[r][c][g] + bz;
            if (col < 256)
              outO[(size_t)(row0 + g) * 256 + col] = v;
            else
              outA[(size_t)(row0 + g) * 128 + (col - 256)] = v;
          }
        }
      }
    }
  }
}

// ---------- GEMM 3: out = samp(bf16, LDS-staged) @ WfO + bo -> f32 ----------
__global__ __launch_bounds__(256) void gemm_out(
    const u16* __restrict__ A, const u16* __restrict__ Wf,
    const float* __restrict__ bias, float* __restrict__ out) {
  __shared__ u16 s_a[128 * 256];  // 64 KB
  const int rb = blockIdx.x;
  const int t = threadIdx.x, l = t & 63, wv = t >> 6;
  const int wr = wv >> 1, wc = wv & 1;
  const int fq = l >> 4, fr = l & 15;
  const int swz = (fr & 7) << 3;
  stage_a_bf16(s_a, A + (size_t)rb * 128 * 256, t);
  __syncthreads();
#pragma unroll
  for (int cb = 0; cb < 2; ++cb) {
    f32x4 acc[4][4];
#pragma unroll
    for (int r = 0; r < 4; ++r)
#pragma unroll
      for (int c = 0; c < 4; ++c) acc[r][c] = f32x4{0.f, 0.f, 0.f, 0.f};
    const u16* bb = Wf + ((size_t)(cb * 8 + wc * 4) * 4 + fq) * 128 + fr * 8;
#pragma unroll
    for (int ks = 0; ks < 8; ++ks) {
      bf16x8 af[4];
#pragma unroll
      for (int r = 0; r < 4; ++r) {
        const int row = wr * 64 + r * 16 + fr;
        af[r] = *(const bf16x8*)(s_a + row * 256 + ((ks * 32 + fq * 8) ^ swz));
      }
      bf16x8 bf[4];
#pragma unroll
      for (int c = 0; c < 4; ++c) bf[c] = *(const bf16x8*)(bb + ks * 8192 + c * 512);
#pragma unroll
      for (int c = 0; c < 4; ++c)
#pragma unroll
        for (int r = 0; r < 4; ++r)
          acc[r][c] = __builtin_amdgcn_mfma_f32_16x16x32_bf16(af[r], bf[c],
                                                              acc[r][c], 0, 0, 0);
    }
    const int rq = fq * 4;
#pragma unroll
    for (int c = 0; c < 4; ++c) {
      const int col = cb * 128 + wc * 64 + c * 16 + fr;
      const float bz = bias[col];
#pragma unroll
      for (int r = 0; r < 4; ++r) {
        const int row0 = rb * 128 + wr * 64 + r * 16 + rq;
#pragma unroll
        for (int g = 0; g < 4; ++g)
          out[(size_t)(row0 + g) * 256 + col] = acc[r][c][g] + bz;
      }
    }
  }
}

// ---------- sampler: VERBATIM round-0 configuration (91.1 us measured) ----------
__global__ __launch_bounds__(256) void msda_sample3(
    const u16* __restrict__ value, const float* __restrict__ off,
    const float* __restrict__ attnl, const float* __restrict__ refp,
    u16* __restrict__ out) {
  __shared__ float s_aw[64 * 17];
  __shared__ uint4 s_idx[16 * 64];
  __shared__ float4 s_w[16 * 64];
  const int t = threadIdx.x;
  const int bq0 = blockIdx.x * 8;

  if (t < 64) {
    const float* lg = attnl + (size_t)(bq0 + (t >> 3)) * 128 + (t & 7) * 16;
    float e[16];
    float m = -1e30f;
#pragma unroll
    for (int i = 0; i < 16; ++i) {
      e[i] = lg[i];
      m = fmaxf(m, e[i]);
    }
    float s = 0.f;
#pragma unroll
    for (int i = 0; i < 16; ++i) {
      e[i] = __expf(e[i] - m);
      s += e[i];
    }
    const float inv = 1.f / s;
#pragma unroll
    for (int i = 0; i < 16; ++i) s_aw[t * 17 + i] = e[i] * inv;
  }
  __syncthreads();

#pragma unroll
  for (int rr = 0; rr < 4; ++rr) {
    const int id = t + rr * 256;
    const int qh = id & 63, lp = id >> 6;
    const int q = qh >> 3, h = qh & 7, lv = lp >> 2, p = lp & 3;
    const int bq = bq0 + q;
    const int Wl = 128 >> lv;
    const int st = (lv == 0) ? 0 : (lv == 1) ? 16384 : (lv == 2) ? 20480 : 21504;
    const float ox = off[(size_t)bq * 256 + ((h * 4 + lv) * 4 + p) * 2];
    const float oy = off[(size_t)bq * 256 + ((h * 4 + lv) * 4 + p) * 2 + 1];
    const float rx = refp[(size_t)bq * 8 + lv * 2];
    const float ry = refp[(size_t)bq * 8 + lv * 2 + 1];
    const float aw = s_aw[qh * 17 + lp];
    const float x = rx * (float)Wl + ox - 0.5f;
    const float y = ry * (float)Wl + oy - 0.5f;
    const float xf = floorf(x), yf = floorf(y);
    const int x0 = (int)xf, y0 = (int)yf;
    const float lw = x - xf, lh = y - yf;
    const float hw = 1.f - lw, hh = 1.f - lh;
    const int ixs[4] = {x0, x0 + 1, x0, x0 + 1};
    const int iys[4] = {y0, y0, y0 + 1, y0 + 1};
    const float wts[4] = {hw * hh, lw * hh, hw * lh, lw * lh};
    u32 rows[4];
    float ws4[4];
#pragma unroll
    for (int c = 0; c < 4; ++c) {
      const int ix = ixs[c], iy = iys[c];
      const bool valid = (ix >= 0) & (ix < Wl) & (iy >= 0) & (iy < Wl);
      int idx = iy * Wl + ix;
      idx = max(0, min(idx, Wl * Wl - 1));
      rows[c] = (u32)(st + idx);
      ws4[c] = valid ? (wts[c] * aw) : 0.f;
    }
    uint4 iv;
    iv.x = rows[0];
    iv.y = rows[1];
    iv.z = rows[2];
    iv.w = rows[3];
    s_idx[lp * 64 + qh] = iv;
    s_w[lp * 64 + qh] = make_float4(ws4[0], ws4[1], ws4[2], ws4[3]);
  }
  __syncthreads();

  const int q = t >> 5, h = (t >> 2) & 7, dg = t & 3;
  const int qh = q * 8 + h;
  const int bq = bq0 + q;
  const u16* vp = value + (size_t)((bq >= LQ_) ? LIN_ : 0) * CDIM + h * 32 + dg * 8;
  float a0 = 0.f, a1 = 0.f, a2 = 0.f, a3 = 0.f;
  float a4 = 0.f, a5 = 0.f, a6 = 0.f, a7 = 0.f;
#pragma unroll 4
  for (int lp = 0; lp < 16; ++lp) {
    const uint4 iv = s_idx[lp * 64 + qh];
    const float4 wv = s_w[lp * 64 + qh];
    const u32 rows[4] = {iv.x, iv.y, iv.z, iv.w};
    const float ww[4] = {wv.x, wv.y, wv.z, wv.w};
#pragma unroll
    for (int c = 0; c < 4; ++c) {
      const uint4 d = *(const uint4*)(vp + (size_t)rows[c] * CDIM);
      const float w = ww[c];
      a0 += w * bflo(d.x);
      a1 += w * bfhi(d.x);
      a2 += w * bflo(d.y);
      a3 += w * bfhi(d.y);
      a4 += w * bflo(d.z);
      a5 += w * bfhi(d.z);
      a6 += w * bflo(d.w);
      a7 += w * bfhi(d.w);
    }
  }
  uint4 o;
  o.x = pack_bf16_rne(a0, a1);
  o.y = pack_bf16_rne(a2, a3);
  o.z = pack_bf16_rne(a4, a5);
  o.w = pack_bf16_rne(a6, a7);
  *(uint4*)(out + (size_t)bq * CDIM + h * 32 + dg * 8) = o;
}

extern "C" void kernel_launch(void* const* d_in, const int* in_sizes, int n_in,
                              void* d_out, int out_size, void* d_ws, size_t ws_size,
                              hipStream_t stream) {
  const float* query = (const float*)d_in[0];
  const float* refp = (const float*)d_in[1];
  const float* inflat = (const float*)d_in[2];
  const float* Wv = (const float*)d_in[3];
  const float* bv = (const float*)d_in[4];
  const float* Wof = (const float*)d_in[5];
  const float* bof = (const float*)d_in[6];
  const float* Wa = (const float*)d_in[7];
  const float* ba = (const float*)d_in[8];
  const float* Wo = (const float*)d_in[9];
  const float* bo = (const float*)d_in[10];
  float* out = (float*)d_out;

  const size_t M = MROWS;

  u16* ws_value = (u16*)d_ws;                    // M*256 bf16 row-major
  float* ws_off = (float*)(ws_value + M * 256);  // M*256 f32
  float* ws_attn = ws_off + M * 256;             // M*128 f32
  u16* ws_samp = (u16*)(ws_attn + M * 128);      // M*256 bf16
  u16* WfV = ws_samp + M * 256;                  // 256*256 bf16
  u16* WfC = WfV + 256 * 256;                    // 256*384 bf16
  u16* WfO = WfC + 384 * 256;                    // 256*256 bf16
  float* bcat = (float*)(WfO + 256 * 256);       // 384 f32

  conv_w<<<dim3(114), dim3(256), 0, stream>>>(Wv, Wof, Wa, Wo, bof, ba, WfV, WfC, WfO,
                                              bcat);
  gemm_vq<<<dim3(680), dim3(256), 0, stream>>>(inflat, WfV, bv, ws_value, query, WfC,
                                               bcat, ws_off, ws_attn);
  msda_sample3<<<dim3(5440), dim3(256), 0, stream>>>(ws_value, ws_off, ws_attn, refp,
                                                     ws_samp);
  gemm_out<<<dim3(340), dim3(256), 0, stream>>>(ws_samp, WfO, bo, out);
}

// Round 5
// 279.607 us; speedup vs baseline: 1.2131x; 1.0259x over previous
//
#include <hip/hip_runtime.h>

typedef unsigned short u16;
typedef unsigned int u32;
typedef short bf16x8 __attribute__((ext_vector_type(8)));
typedef float f32x4 __attribute__((ext_vector_type(4)));

#define LQ_ 21760
#define LIN_ 21760
#define CDIM 256
#define MROWS (2 * LQ_)  // 43520

__device__ __forceinline__ u16 f2bf(float f) {
  u32 u;
  __builtin_memcpy(&u, &f, 4);
  u32 r = (u + 0x7fffu + ((u >> 16) & 1u)) >> 16;
  return (u16)r;
}
__device__ __forceinline__ u32 pack_bf16_rne(float a, float b) {
  return (u32)f2bf(a) | ((u32)f2bf(b) << 16);
}
__device__ __forceinline__ float bflo(u32 u) {
  u32 v = u << 16;
  float f;
  __builtin_memcpy(&f, &v, 4);
  return f;
}
__device__ __forceinline__ float bfhi(u32 u) {
  u32 v = u & 0xffff0000u;
  float f;
  __builtin_memcpy(&f, &v, 4);
  return f;
}

// ---------- weight pre-conversion to bf16 fragment-chunk layout (B side) ----------
// chunkIdx = ks*(N/4) + (n>>4)*4 + ((k>>3)&3); element (n&15)*8 + (k&7).
__device__ __forceinline__ void conv_one(const float* W0, const float* W1, u16* Wf,
                                         int N, int split, int blk, int t) {
  const int tid = blk * 256 + t;
  if (tid >= N * 32) return;
  const int n = tid >> 5, kcg = tid & 31;
  float w[8];
#pragma unroll
  for (int j = 0; j < 8; ++j) {
    const int k = kcg * 8 + j;
    w[j] = (n < split) ? W0[(size_t)k * split + n]
                       : W1[(size_t)k * (N - split) + (n - split)];
  }
  uint4 pk;
  pk.x = pack_bf16_rne(w[0], w[1]);
  pk.y = pack_bf16_rne(w[2], w[3]);
  pk.z = pack_bf16_rne(w[4], w[5]);
  pk.w = pack_bf16_rne(w[6], w[7]);
  const int ks = kcg >> 2, kcr = kcg & 3, c = n >> 4;
  const int chunk = ks * (N / 4) + c * 4 + kcr;
  *(uint4*)(Wf + (size_t)chunk * 128 + (n & 15) * 8) = pk;
}

// ---------- weights-only pre-conversion ----------
__global__ __launch_bounds__(256) void conv_w(
    const float* __restrict__ Wv, const float* __restrict__ Wof,
    const float* __restrict__ Wa, const float* __restrict__ Wo,
    const float* __restrict__ bof, const float* __restrict__ ba,
    u16* __restrict__ WfV, u16* __restrict__ WfC, u16* __restrict__ WfO,
    float* __restrict__ bcat) {
  const int b = blockIdx.x, t = threadIdx.x;
  if (b < 32) {
    conv_one(Wv, Wv, WfV, 256, 256, b, t);
    return;
  }
  if (b < 80) {
    conv_one(Wof, Wa, WfC, 384, 256, b - 32, t);
    return;
  }
  if (b < 112) {
    conv_one(Wo, Wo, WfO, 256, 256, b - 80, t);
    return;
  }
  const int i = (b - 112) * 256 + t;
  if (i < 384) bcat[i] = (i < 256) ? bof[i] : ba[i - 256];
}

// ---------- LDS A-panel helpers (64-row tiles, 32 KB) ----------
// LDS layout: 64 rows x 256 bf16, elem-col XOR-swizzled by ((row&7)<<3) in 8-elem
// (16 B) granules; both ds_write (staging) and ds_read (frags) hit the 8-cycle
// bank floor with no extra conflicts (measured 0 on the 128-row variant).
__device__ __forceinline__ void stage_a_f32_64(u16* s_a, const float* __restrict__ ga,
                                               int t) {
#pragma unroll
  for (int it = 0; it < 8; ++it) {
    const int idx = it * 256 + t;
    const int row = idx >> 5, cc = idx & 31;
    const float4 f0 = *(const float4*)(ga + (size_t)row * 256 + cc * 8);
    const float4 f1 = *(const float4*)(ga + (size_t)row * 256 + cc * 8 + 4);
    uint4 pk;
    pk.x = pack_bf16_rne(f0.x, f0.y);
    pk.y = pack_bf16_rne(f0.z, f0.w);
    pk.z = pack_bf16_rne(f1.x, f1.y);
    pk.w = pack_bf16_rne(f1.z, f1.w);
    *(uint4*)(s_a + row * 256 + ((cc * 8) ^ ((row & 7) << 3))) = pk;
  }
}
__device__ __forceinline__ void stage_a_bf16_64(u16* s_a, const u16* __restrict__ ga,
                                                int t) {
#pragma unroll
  for (int it = 0; it < 8; ++it) {
    const int idx = it * 256 + t;
    const int row = idx >> 5, cc = idx & 31;
    const uint4 pk = *(const uint4*)(ga + (size_t)row * 256 + cc * 8);
    *(uint4*)(s_a + row * 256 + ((cc * 8) ^ ((row & 7) << 3))) = pk;
  }
}

// ---------- GEMM 1+2: 64-row tiles, A staged f32->bf16 in LDS ----------
// 4 waves: wr in {0,1} = 32-row half, wc in {0,1} = 64-col half of 128-col cb.
// acc[2][4] = 32 VGPR -> ~100 live regs -> 4 waves/SIMD; LDS 32 KB -> 4 blocks/CU.
// blocks [0,680): value = inflat @ WfV + bv (bf16 out, N=256, 2 cb)
// blocks [680,1360): [off|attn] = query @ WfC + bcat (f32 split, N=384, 3 cb)
__global__ __launch_bounds__(256, 4) void gemm_vq(
    const float* __restrict__ Ai, const u16* __restrict__ WfV,
    const float* __restrict__ bv, u16* __restrict__ outV,
    const float* __restrict__ Aq, const u16* __restrict__ WfC,
    const float* __restrict__ bcat, float* __restrict__ outO,
    float* __restrict__ outA) {
  __shared__ u16 s_a[64 * 256];  // 32 KB
  const int t = threadIdx.x, l = t & 63, wv = t >> 6;
  const int wr = wv >> 1, wc = wv & 1;
  const int fq = l >> 4, fr = l & 15;
  const int swz = (fr & 7) << 3;

  if (blockIdx.x < 680) {
    const int rb = blockIdx.x;
    stage_a_f32_64(s_a, Ai + (size_t)rb * 64 * 256, t);
    __syncthreads();
#pragma unroll
    for (int cb = 0; cb < 2; ++cb) {
      f32x4 acc[2][4];
#pragma unroll
      for (int r = 0; r < 2; ++r)
#pragma unroll
        for (int c = 0; c < 4; ++c) acc[r][c] = f32x4{0.f, 0.f, 0.f, 0.f};
      const u16* bb = WfV + ((size_t)(cb * 8 + wc * 4) * 4 + fq) * 128 + fr * 8;
#pragma unroll
      for (int ks = 0; ks < 8; ++ks) {
        bf16x8 af[2];
#pragma unroll
        for (int r = 0; r < 2; ++r) {
          const int row = wr * 32 + r * 16 + fr;
          af[r] = *(const bf16x8*)(s_a + row * 256 + ((ks * 32 + fq * 8) ^ swz));
        }
        bf16x8 bf[4];
#pragma unroll
        for (int c = 0; c < 4; ++c) bf[c] = *(const bf16x8*)(bb + ks * 8192 + c * 512);
#pragma unroll
        for (int c = 0; c < 4; ++c)
#pragma unroll
          for (int r = 0; r < 2; ++r)
            acc[r][c] = __builtin_amdgcn_mfma_f32_16x16x32_bf16(af[r], bf[c],
                                                                acc[r][c], 0, 0, 0);
      }
      const int rq = fq * 4;
#pragma unroll
      for (int c = 0; c < 4; ++c) {
        const int col = cb * 128 + wc * 64 + c * 16 + fr;
        const float bz = bv[col];
#pragma unroll
        for (int r = 0; r < 2; ++r) {
          const int row0 = rb * 64 + wr * 32 + r * 16 + rq;
#pragma unroll
          for (int g = 0; g < 4; ++g)
            outV[(size_t)(row0 + g) * 256 + col] = f2bf(acc[r][c][g] + bz);
        }
      }
    }
  } else {
    const int rb = blockIdx.x - 680;
    stage_a_f32_64(s_a, Aq + (size_t)rb * 64 * 256, t);
    __syncthreads();
#pragma unroll
    for (int cb = 0; cb < 3; ++cb) {
      f32x4 acc[2][4];
#pragma unroll
      for (int r = 0; r < 2; ++r)
#pragma unroll
        for (int c = 0; c < 4; ++c) acc[r][c] = f32x4{0.f, 0.f, 0.f, 0.f};
      const u16* bb = WfC + ((size_t)(cb * 8 + wc * 4) * 4 + fq) * 128 + fr * 8;
#pragma unroll
      for (int ks = 0; ks < 8; ++ks) {
        bf16x8 af[2];
#pragma unroll
        for (int r = 0; r < 2; ++r) {
          const int row = wr * 32 + r * 16 + fr;
          af[r] = *(const bf16x8*)(s_a + row * 256 + ((ks * 32 + fq * 8) ^ swz));
        }
        bf16x8 bf[4];
#pragma unroll
        for (int c = 0; c < 4; ++c) bf[c] = *(const bf16x8*)(bb + ks * 12288 + c * 512);
#pragma unroll
        for (int c = 0; c < 4; ++c)
#pragma unroll
          for (int r = 0; r < 2; ++r)
            acc[r][c] = __builtin_amdgcn_mfma_f32_16x16x32_bf16(af[r], bf[c],
                                                                acc[r][c], 0, 0, 0);
      }
      const int rq = fq * 4;
#pragma unroll
      for (int c = 0; c < 4; ++c) {
        const int col = cb * 128 + wc * 64 + c * 16 + fr;
        const float bz = bcat[col];
#pragma unroll
        for (int r = 0; r < 2; ++r) {
          const int row0 = rb * 64 + wr * 32 + r * 16 + rq;
#pragma unroll
          for (int g = 0; g < 4; ++g) {
            const float v = acc[r][c][g] + bz;
            if (col < 256)
              outO[(size_t)(row0 + g) * 256 + col] = v;
            else
              outA[(size_t)(row0 + g) * 128 + (col - 256)] = v;
          }
        }
      }
    }
  }
}

// ---------- GEMM 3: 64-row tiles, out = samp(bf16, LDS-staged) @ WfO + bo -> f32 ----
__global__ __launch_bounds__(256, 4) void gemm_out(
    const u16* __restrict__ A, const u16* __restrict__ Wf,
    const float* __restrict__ bias, float* __restrict__ out) {
  __shared__ u16 s_a[64 * 256];  // 32 KB
  const int rb = blockIdx.x;
  const int t = threadIdx.x, l = t & 63, wv = t >> 6;
  const int wr = wv >> 1, wc = wv & 1;
  const int fq = l >> 4, fr = l & 15;
  const int swz = (fr & 7) << 3;
  stage_a_bf16_64(s_a, A + (size_t)rb * 64 * 256, t);
  __syncthreads();
#pragma unroll
  for (int cb = 0; cb < 2; ++cb) {
    f32x4 acc[2][4];
#pragma unroll
    for (int r = 0; r < 2; ++r)
#pragma unroll
      for (int c = 0; c < 4; ++c) acc[r][c] = f32x4{0.f, 0.f, 0.f, 0.f};
    const u16* bb = Wf + ((size_t)(cb * 8 + wc * 4) * 4 + fq) * 128 + fr * 8;
#pragma unroll
    for (int ks = 0; ks < 8; ++ks) {
      bf16x8 af[2];
#pragma unroll
      for (int r = 0; r < 2; ++r) {
        const int row = wr * 32 + r * 16 + fr;
        af[r] = *(const bf16x8*)(s_a + row * 256 + ((ks * 32 + fq * 8) ^ swz));
      }
      bf16x8 bf[4];
#pragma unroll
      for (int c = 0; c < 4; ++c) bf[c] = *(const bf16x8*)(bb + ks * 8192 + c * 512);
#pragma unroll
      for (int c = 0; c < 4; ++c)
#pragma unroll
        for (int r = 0; r < 2; ++r)
          acc[r][c] = __builtin_amdgcn_mfma_f32_16x16x32_bf16(af[r], bf[c],
                                                              acc[r][c], 0, 0, 0);
    }
    const int rq = fq * 4;
#pragma unroll
    for (int c = 0; c < 4; ++c) {
      const int col = cb * 128 + wc * 64 + c * 16 + fr;
      const float bz = bias[col];
#pragma unroll
      for (int r = 0; r < 2; ++r) {
        const int row0 = rb * 64 + wr * 32 + r * 16 + rq;
#pragma unroll
        for (int g = 0; g < 4; ++g)
          out[(size_t)(row0 + g) * 256 + col] = acc[r][c][g] + bz;
      }
    }
  }
}

// ---------- sampler: VERBATIM best-known configuration (86-91 us measured) ----------
__global__ __launch_bounds__(256) void msda_sample3(
    const u16* __restrict__ value, const float* __restrict__ off,
    const float* __restrict__ attnl, const float* __restrict__ refp,
    u16* __restrict__ out) {
  __shared__ float s_aw[64 * 17];
  __shared__ uint4 s_idx[16 * 64];
  __shared__ float4 s_w[16 * 64];
  const int t = threadIdx.x;
  const int bq0 = blockIdx.x * 8;

  if (t < 64) {
    const float* lg = attnl + (size_t)(bq0 + (t >> 3)) * 128 + (t & 7) * 16;
    float e[16];
    float m = -1e30f;
#pragma unroll
    for (int i = 0; i < 16; ++i) {
      e[i] = lg[i];
      m = fmaxf(m, e[i]);
    }
    float s = 0.f;
#pragma unroll
    for (int i = 0; i < 16; ++i) {
      e[i] = __expf(e[i] - m);
      s += e[i];
    }
    const float inv = 1.f / s;
#pragma unroll
    for (int i = 0; i < 16; ++i) s_aw[t * 17 + i] = e[i] * inv;
  }
  __syncthreads();

#pragma unroll
  for (int rr = 0; rr < 4; ++rr) {
    const int id = t + rr * 256;
    const int qh = id & 63, lp = id >> 6;
    const int q = qh >> 3, h = qh & 7, lv = lp >> 2, p = lp & 3;
    const int bq = bq0 + q;
    const int Wl = 128 >> lv;
    const int st = (lv == 0) ? 0 : (lv == 1) ? 16384 : (lv == 2) ? 20480 : 21504;
    const float ox = off[(size_t)bq * 256 + ((h * 4 + lv) * 4 + p) * 2];
    const float oy = off[(size_t)bq * 256 + ((h * 4 + lv) * 4 + p) * 2 + 1];
    const float rx = refp[(size_t)bq * 8 + lv * 2];
    const float ry = refp[(size_t)bq * 8 + lv * 2 + 1];
    const float aw = s_aw[qh * 17 + lp];
    const float x = rx * (float)Wl + ox - 0.5f;
    const float y = ry * (float)Wl + oy - 0.5f;
    const float xf = floorf(x), yf = floorf(y);
    const int x0 = (int)xf, y0 = (int)yf;
    const float lw = x - xf, lh = y - yf;
    const float hw = 1.f - lw, hh = 1.f - lh;
    const int ixs[4] = {x0, x0 + 1, x0, x0 + 1};
    const int iys[4] = {y0, y0, y0 + 1, y0 + 1};
    const float wts[4] = {hw * hh, lw * hh, hw * lh, lw * lh};
    u32 rows[4];
    float ws4[4];
#pragma unroll
    for (int c = 0; c < 4; ++c) {
      const int ix = ixs[c], iy = iys[c];
      const bool valid = (ix >= 0) & (ix < Wl) & (iy >= 0) & (iy < Wl);
      int idx = iy * Wl + ix;
      idx = max(0, min(idx, Wl * Wl - 1));
      rows[c] = (u32)(st + idx);
      ws4[c] = valid ? (wts[c] * aw) : 0.f;
    }
    uint4 iv;
    iv.x = rows[0];
    iv.y = rows[1];
    iv.z = rows[2];
    iv.w = rows[3];
    s_idx[lp * 64 + qh] = iv;
    s_w[lp * 64 + qh] = make_float4(ws4[0], ws4[1], ws4[2], ws4[3]);
  }
  __syncthreads();

  const int q = t >> 5, h = (t >> 2) & 7, dg = t & 3;
  const int qh = q * 8 + h;
  const int bq = bq0 + q;
  const u16* vp = value + (size_t)((bq >= LQ_) ? LIN_ : 0) * CDIM + h * 32 + dg * 8;
  float a0 = 0.f, a1 = 0.f, a2 = 0.f, a3 = 0.f;
  float a4 = 0.f, a5 = 0.f, a6 = 0.f, a7 = 0.f;
#pragma unroll 4
  for (int lp = 0; lp < 16; ++lp) {
    const uint4 iv = s_idx[lp * 64 + qh];
    const float4 wv = s_w[lp * 64 + qh];
    const u32 rows[4] = {iv.x, iv.y, iv.z, iv.w};
    const float ww[4] = {wv.x, wv.y, wv.z, wv.w};
#pragma unroll
    for (int c = 0; c < 4; ++c) {
      const uint4 d = *(const uint4*)(vp + (size_t)rows[c] * CDIM);
      const float w = ww[c];
      a0 += w * bflo(d.x);
      a1 += w * bfhi(d.x);
      a2 += w * bflo(d.y);
      a3 += w * bfhi(d.y);
      a4 += w * bflo(d.z);
      a5 += w * bfhi(d.z);
      a6 += w * bflo(d.w);
      a7 += w * bfhi(d.w);
    }
  }
  uint4 o;
  o.x = pack_bf16_rne(a0, a1);
  o.y = pack_bf16_rne(a2, a3);
  o.z = pack_bf16_rne(a4, a5);
  o.w = pack_bf16_rne(a6, a7);
  *(uint4*)(out + (size_t)bq * CDIM + h * 32 + dg * 8) = o;
}

extern "C" void kernel_launch(void* const* d_in, const int* in_sizes, int n_in,
                              void* d_out, int out_size, void* d_ws, size_t ws_size,
                              hipStream_t stream) {
  const float* query = (const float*)d_in[0];
  const float* refp = (const float*)d_in[1];
  const float* inflat = (const float*)d_in[2];
  const float* Wv = (const float*)d_in[3];
  const float* bv = (const float*)d_in[4];
  const float* Wof = (const float*)d_in[5];
  const float* bof = (const float*)d_in[6];
  const float* Wa = (const float*)d_in[7];
  const float* ba = (const float*)d_in[8];
  const float* Wo = (const float*)d_in[9];
  const float* bo = (const float*)d_in[10];
  float* out = (float*)d_out;

  const size_t M = MROWS;

  u16* ws_value = (u16*)d_ws;                    // M*256 bf16 row-major
  float* ws_off = (float*)(ws_value + M * 256);  // M*256 f32
  float* ws_attn = ws_off + M * 256;             // M*128 f32
  u16* ws_samp = (u16*)(ws_attn + M * 128);      // M*256 bf16
  u16* WfV = ws_samp + M * 256;                  // 256*256 bf16
  u16* WfC = WfV + 256 * 256;                    // 256*384 bf16
  u16* WfO = WfC + 384 * 256;                    // 256*256 bf16
  float* bcat = (float*)(WfO + 256 * 256);       // 384 f32

  conv_w<<<dim3(114), dim3(256), 0, stream>>>(Wv, Wof, Wa, Wo, bof, ba, WfV, WfC, WfO,
                                              bcat);
  gemm_vq<<<dim3(1360), dim3(256), 0, stream>>>(inflat, WfV, bv, ws_value, query, WfC,
                                                bcat, ws_off, ws_attn);
  msda_sample3<<<dim3(5440), dim3(256), 0, stream>>>(ws_value, ws_off, ws_attn, refp,
                                                     ws_samp);
  gemm_out<<<dim3(680), dim3(256), 0, stream>>>(ws_samp, WfO, bo, out);
}

// Round 9
// 277.565 us; speedup vs baseline: 1.2220x; 1.0074x over previous
//
#include <hip/hip_runtime.h>

typedef unsigned short u16;
typedef unsigned int u32;
typedef short bf16x8 __attribute__((ext_vector_type(8)));
typedef float f32x4 __attribute__((ext_vector_type(4)));

#define LQ_ 21760
#define LIN_ 21760
#define CDIM 256
#define MROWS (2 * LQ_)  // 43520

__device__ __forceinline__ u16 f2bf(float f) {
  u32 u;
  __builtin_memcpy(&u, &f, 4);
  u32 r = (u + 0x7fffu + ((u >> 16) & 1u)) >> 16;
  return (u16)r;
}
__device__ __forceinline__ u32 pack_bf16_rne(float a, float b) {
  return (u32)f2bf(a) | ((u32)f2bf(b) << 16);
}
__device__ __forceinline__ float bflo(u32 u) {
  u32 v = u << 16;
  float f;
  __builtin_memcpy(&f, &v, 4);
  return f;
}
__device__ __forceinline__ float bfhi(u32 u) {
  u32 v = u & 0xffff0000u;
  float f;
  __builtin_memcpy(&f, &v, 4);
  return f;
}

// ---------- weight pre-conversion to bf16 fragment-chunk layout (B side) ----------
// chunkIdx = ks*(N/4) + (n>>4)*4 + ((k>>3)&3); element (n&15)*8 + (k&7).
__device__ __forceinline__ void conv_one(const float* W0, const float* W1, u16* Wf,
                                         int N, int split, int blk, int t) {
  const int tid = blk * 256 + t;
  if (tid >= N * 32) return;
  const int n = tid >> 5, kcg = tid & 31;
  float w[8];
#pragma unroll
  for (int j = 0; j < 8; ++j) {
    const int k = kcg * 8 + j;
    w[j] = (n < split) ? W0[(size_t)k * split + n]
                       : W1[(size_t)k * (N - split) + (n - split)];
  }
  uint4 pk;
  pk.x = pack_bf16_rne(w[0], w[1]);
  pk.y = pack_bf16_rne(w[2], w[3]);
  pk.z = pack_bf16_rne(w[4], w[5]);
  pk.w = pack_bf16_rne(w[6], w[7]);
  const int ks = kcg >> 2, kcr = kcg & 3, c = n >> 4;
  const int chunk = ks * (N / 4) + c * 4 + kcr;
  *(uint4*)(Wf + (size_t)chunk * 128 + (n & 15) * 8) = pk;
}

// ---------- weights-only pre-conversion ----------
__global__ __launch_bounds__(256) void conv_w(
    const float* __restrict__ Wv, const float* __restrict__ Wof,
    const float* __restrict__ Wa, const float* __restrict__ Wo,
    const float* __restrict__ bof, const float* __restrict__ ba,
    u16* __restrict__ WfV, u16* __restrict__ WfC, u16* __restrict__ WfO,
    float* __restrict__ bcat) {
  const int b = blockIdx.x, t = threadIdx.x;
  if (b < 32) {
    conv_one(Wv, Wv, WfV, 256, 256, b, t);
    return;
  }
  if (b < 80) {
    conv_one(Wof, Wa, WfC, 384, 256, b - 32, t);
    return;
  }
  if (b < 112) {
    conv_one(Wo, Wo, WfO, 256, 256, b - 80, t);
    return;
  }
  const int i = (b - 112) * 256 + t;
  if (i < 384) bcat[i] = (i < 256) ? bof[i] : ba[i - 256];
}

// ---------- LDS A-panel staging (64-row tiles, 32 KB) ----------
// LDS layout: 64 rows x 256 bf16, elem-col XOR-swizzled by ((row&7)<<3) in 8-elem
// (16 B) granules; staging ds_write and frag ds_read both conflict-free (measured 0).
__device__ __forceinline__ void stage_a_f32_64(u16* s_a, const float* __restrict__ ga,
                                               int t) {
#pragma unroll
  for (int it = 0; it < 8; ++it) {
    const int idx = it * 256 + t;
    const int row = idx >> 5, cc = idx & 31;
    const float4 f0 = *(const float4*)(ga + (size_t)row * 256 + cc * 8);
    const float4 f1 = *(const float4*)(ga + (size_t)row * 256 + cc * 8 + 4);
    uint4 pk;
    pk.x = pack_bf16_rne(f0.x, f0.y);
    pk.y = pack_bf16_rne(f0.z, f0.w);
    pk.z = pack_bf16_rne(f1.x, f1.y);
    pk.w = pack_bf16_rne(f1.z, f1.w);
    *(uint4*)(s_a + row * 256 + ((cc * 8) ^ ((row & 7) << 3))) = pk;
  }
}
__device__ __forceinline__ void stage_a_bf16_64(u16* s_a, const u16* __restrict__ ga,
                                                int t) {
#pragma unroll
  for (int it = 0; it < 8; ++it) {
    const int idx = it * 256 + t;
    const int row = idx >> 5, cc = idx & 31;
    const uint4 pk = *(const uint4*)(ga + (size_t)row * 256 + cc * 8);
    *(uint4*)(s_a + row * 256 + ((cc * 8) ^ ((row & 7) << 3))) = pk;
  }
}

// ---------- GEMM 1: value = inflat @ WfV + bv (bf16 out, N=256, 2 cb) ----------
// Round-5 gemm_vq value-half, now a standalone dispatch for per-kernel counters.
__global__ __launch_bounds__(256, 4) void gemm_v(
    const float* __restrict__ Ai, const u16* __restrict__ WfV,
    const float* __restrict__ bv, u16* __restrict__ outV) {
  __shared__ u16 s_a[64 * 256];  // 32 KB
  const int t = threadIdx.x, l = t & 63, wv = t >> 6;
  const int wr = wv >> 1, wc = wv & 1;
  const int fq = l >> 4, fr = l & 15;
  const int swz = (fr & 7) << 3;
  const int rb = blockIdx.x;
  stage_a_f32_64(s_a, Ai + (size_t)rb * 64 * 256, t);
  __syncthreads();
#pragma unroll
  for (int cb = 0; cb < 2; ++cb) {
    f32x4 acc[2][4];
#pragma unroll
    for (int r = 0; r < 2; ++r)
#pragma unroll
      for (int c = 0; c < 4; ++c) acc[r][c] = f32x4{0.f, 0.f, 0.f, 0.f};
    const u16* bb = WfV + ((size_t)(cb * 8 + wc * 4) * 4 + fq) * 128 + fr * 8;
#pragma unroll
    for (int ks = 0; ks < 8; ++ks) {
      bf16x8 af[2];
#pragma unroll
      for (int r = 0; r < 2; ++r) {
        const int row = wr * 32 + r * 16 + fr;
        af[r] = *(const bf16x8*)(s_a + row * 256 + ((ks * 32 + fq * 8) ^ swz));
      }
      bf16x8 bf[4];
#pragma unroll
      for (int c = 0; c < 4; ++c) bf[c] = *(const bf16x8*)(bb + ks * 8192 + c * 512);
#pragma unroll
      for (int c = 0; c < 4; ++c)
#pragma unroll
        for (int r = 0; r < 2; ++r)
          acc[r][c] = __builtin_amdgcn_mfma_f32_16x16x32_bf16(af[r], bf[c],
                                                              acc[r][c], 0, 0, 0);
    }
    const int rq = fq * 4;
#pragma unroll
    for (int c = 0; c < 4; ++c) {
      const int col = cb * 128 + wc * 64 + c * 16 + fr;
      const float bz = bv[col];
#pragma unroll
      for (int r = 0; r < 2; ++r) {
        const int row0 = rb * 64 + wr * 32 + r * 16 + rq;
#pragma unroll
        for (int g = 0; g < 4; ++g)
          outV[(size_t)(row0 + g) * 256 + col] = f2bf(acc[r][c][g] + bz);
      }
    }
  }
}

// ---------- GEMM 2: [off|attn] = query @ WfC + bcat (f32 split, N=384, 3 cb) ------
// Round-5 gemm_vq query-half, standalone dispatch.
__global__ __launch_bounds__(256, 4) void gemm_q(
    const float* __restrict__ Aq, const u16* __restrict__ WfC,
    const float* __restrict__ bcat, float* __restrict__ outO,
    float* __restrict__ outA) {
  __shared__ u16 s_a[64 * 256];  // 32 KB
  const int t = threadIdx.x, l = t & 63, wv = t >> 6;
  const int wr = wv >> 1, wc = wv & 1;
  const int fq = l >> 4, fr = l & 15;
  const int swz = (fr & 7) << 3;
  const int rb = blockIdx.x;
  stage_a_f32_64(s_a, Aq + (size_t)rb * 64 * 256, t);
  __syncthreads();
#pragma unroll
  for (int cb = 0; cb < 3; ++cb) {
    f32x4 acc[2][4];
#pragma unroll
    for (int r = 0; r < 2; ++r)
#pragma unroll
      for (int c = 0; c < 4; ++c) acc[r][c] = f32x4{0.f, 0.f, 0.f, 0.f};
    const u16* bb = WfC + ((size_t)(cb * 8 + wc * 4) * 4 + fq) * 128 + fr * 8;
#pragma unroll
    for (int ks = 0; ks < 8; ++ks) {
      bf16x8 af[2];
#pragma unroll
      for (int r = 0; r < 2; ++r) {
        const int row = wr * 32 + r * 16 + fr;
        af[r] = *(const bf16x8*)(s_a + row * 256 + ((ks * 32 + fq * 8) ^ swz));
      }
      bf16x8 bf[4];
#pragma unroll
      for (int c = 0; c < 4; ++c) bf[c] = *(const bf16x8*)(bb + ks * 12288 + c * 512);
#pragma unroll
      for (int c = 0; c < 4; ++c)
#pragma unroll
        for (int r = 0; r < 2; ++r)
          acc[r][c] = __builtin_amdgcn_mfma_f32_16x16x32_bf16(af[r], bf[c],
                                                              acc[r][c], 0, 0, 0);
    }
    const int rq = fq * 4;
#pragma unroll
    for (int c = 0; c < 4; ++c) {
      const int col = cb * 128 + wc * 64 + c * 16 + fr;
      const float bz = bcat[col];
#pragma unroll
      for (int r = 0; r < 2; ++r) {
        const int row0 = rb * 64 + wr * 32 + r * 16 + rq;
#pragma unroll
        for (int g = 0; g < 4; ++g) {
          const float v = acc[r][c][g] + bz;
          if (col < 256)
            outO[(size_t)(row0 + g) * 256 + col] = v;
          else
            outA[(size_t)(row0 + g) * 128 + (col - 256)] = v;
        }
      }
    }
  }
}

// ---------- GEMM 3: 64-row tiles, out = samp(bf16, LDS-staged) @ WfO + bo -> f32 ----
__global__ __launch_bounds__(256, 4) void gemm_out(
    const u16* __restrict__ A, const u16* __restrict__ Wf,
    const float* __restrict__ bias, float* __restrict__ out) {
  __shared__ u16 s_a[64 * 256];  // 32 KB
  const int rb = blockIdx.x;
  const int t = threadIdx.x, l = t & 63, wv = t >> 6;
  const int wr = wv >> 1, wc = wv & 1;
  const int fq = l >> 4, fr = l & 15;
  const int swz = (fr & 7) << 3;
  stage_a_bf16_64(s_a, A + (size_t)rb * 64 * 256, t);
  __syncthreads();
#pragma unroll
  for (int cb = 0; cb < 2; ++cb) {
    f32x4 acc[2][4];
#pragma unroll
    for (int r = 0; r < 2; ++r)
#pragma unroll
      for (int c = 0; c < 4; ++c) acc[r][c] = f32x4{0.f, 0.f, 0.f, 0.f};
    const u16* bb = Wf + ((size_t)(cb * 8 + wc * 4) * 4 + fq) * 128 + fr * 8;
#pragma unroll
    for (int ks = 0; ks < 8; ++ks) {
      bf16x8 af[2];
#pragma unroll
      for (int r = 0; r < 2; ++r) {
        const int row = wr * 32 + r * 16 + fr;
        af[r] = *(const bf16x8*)(s_a + row * 256 + ((ks * 32 + fq * 8) ^ swz));
      }
      bf16x8 bf[4];
#pragma unroll
      for (int c = 0; c < 4; ++c) bf[c] = *(const bf16x8*)(bb + ks * 8192 + c * 512);
#pragma unroll
      for (int c = 0; c < 4; ++c)
#pragma unroll
        for (int r = 0; r < 2; ++r)
          acc[r][c] = __builtin_amdgcn_mfma_f32_16x16x32_bf16(af[r], bf[c],
                                                              acc[r][c], 0, 0, 0);
    }
    const int rq = fq * 4;
#pragma unroll
    for (int c = 0; c < 4; ++c) {
      const int col = cb * 128 + wc * 64 + c * 16 + fr;
      const float bz = bias[col];
#pragma unroll
      for (int r = 0; r < 2; ++r) {
        const int row0 = rb * 64 + wr * 32 + r * 16 + rq;
#pragma unroll
        for (int g = 0; g < 4; ++g)
          out[(size_t)(row0 + g) * 256 + col] = acc[r][c][g] + bz;
      }
    }
  }
}

// ---------- sampler: VERBATIM best-known configuration (85.6-86.4 us measured) ------
__global__ __launch_bounds__(256) void msda_sample3(
    const u16* __restrict__ value, const float* __restrict__ off,
    const float* __restrict__ attnl, const float* __restrict__ refp,
    u16* __restrict__ out) {
  __shared__ float s_aw[64 * 17];
  __shared__ uint4 s_idx[16 * 64];
  __shared__ float4 s_w[16 * 64];
  const int t = threadIdx.x;
  const int bq0 = blockIdx.x * 8;

  if (t < 64) {
    const float* lg = attnl + (size_t)(bq0 + (t >> 3)) * 128 + (t & 7) * 16;
    float e[16];
    float m = -1e30f;
#pragma unroll
    for (int i = 0; i < 16; ++i) {
      e[i] = lg[i];
      m = fmaxf(m, e[i]);
    }
    float s = 0.f;
#pragma unroll
    for (int i = 0; i < 16; ++i) {
      e[i] = __expf(e[i] - m);
      s += e[i];
    }
    const float inv = 1.f / s;
#pragma unroll
    for (int i = 0; i < 16; ++i) s_aw[t * 17 + i] = e[i] * inv;
  }
  __syncthreads();

#pragma unroll
  for (int rr = 0; rr < 4; ++rr) {
    const int id = t + rr * 256;
    const int qh = id & 63, lp = id >> 6;
    const int q = qh >> 3, h = qh & 7, lv = lp >> 2, p = lp & 3;
    const int bq = bq0 + q;
    const int Wl = 128 >> lv;
    const int st = (lv == 0) ? 0 : (lv == 1) ? 16384 : (lv == 2) ? 20480 : 21504;
    const float ox = off[(size_t)bq * 256 + ((h * 4 + lv) * 4 + p) * 2];
    const float oy = off[(size_t)bq * 256 + ((h * 4 + lv) * 4 + p) * 2 + 1];
    const float rx = refp[(size_t)bq * 8 + lv * 2];
    const float ry = refp[(size_t)bq * 8 + lv * 2 + 1];
    const float aw = s_aw[qh * 17 + lp];
    const float x = rx * (float)Wl + ox - 0.5f;
    const float y = ry * (float)Wl + oy - 0.5f;
    const float xf = floorf(x), yf = floorf(y);
    const int x0 = (int)xf, y0 = (int)yf;
    const float lw = x - xf, lh = y - yf;
    const float hw = 1.f - lw, hh = 1.f - lh;
    const int ixs[4] = {x0, x0 + 1, x0, x0 + 1};
    const int iys[4] = {y0, y0, y0 + 1, y0 + 1};
    const float wts[4] = {hw * hh, lw * hh, hw * lh, lw * lh};
    u32 rows[4];
    float ws4[4];
#pragma unroll
    for (int c = 0; c < 4; ++c) {
      const int ix = ixs[c], iy = iys[c];
      const bool valid = (ix >= 0) & (ix < Wl) & (iy >= 0) & (iy < Wl);
      int idx = iy * Wl + ix;
      idx = max(0, min(idx, Wl * Wl - 1));
      rows[c] = (u32)(st + idx);
      ws4[c] = valid ? (wts[c] * aw) : 0.f;
    }
    uint4 iv;
    iv.x = rows[0];
    iv.y = rows[1];
    iv.z = rows[2];
    iv.w = rows[3];
    s_idx[lp * 64 + qh] = iv;
    s_w[lp * 64 + qh] = make_float4(ws4[0], ws4[1], ws4[2], ws4[3]);
  }
  __syncthreads();

  const int q = t >> 5, h = (t >> 2) & 7, dg = t & 3;
  const int qh = q * 8 + h;
  const int bq = bq0 + q;
  const u16* vp = value + (size_t)((bq >= LQ_) ? LIN_ : 0) * CDIM + h * 32 + dg * 8;
  float a0 = 0.f, a1 = 0.f, a2 = 0.f, a3 = 0.f;
  float a4 = 0.f, a5 = 0.f, a6 = 0.f, a7 = 0.f;
#pragma unroll 4
  for (int lp = 0; lp < 16; ++lp) {
    const uint4 iv = s_idx[lp * 64 + qh];
    const float4 wv = s_w[lp * 64 + qh];
    const u32 rows[4] = {iv.x, iv.y, iv.z, iv.w};
    const float ww[4] = {wv.x, wv.y, wv.z, wv.w};
#pragma unroll
    for (int c = 0; c < 4; ++c) {
      const uint4 d = *(const uint4*)(vp + (size_t)rows[c] * CDIM);
      const float w = ww[c];
      a0 += w * bflo(d.x);
      a1 += w * bfhi(d.x);
      a2 += w * bflo(d.y);
      a3 += w * bfhi(d.y);
      a4 += w * bflo(d.z);
      a5 += w * bfhi(d.z);
      a6 += w * bflo(d.w);
      a7 += w * bfhi(d.w);
    }
  }
  uint4 o;
  o.x = pack_bf16_rne(a0, a1);
  o.y = pack_bf16_rne(a2, a3);
  o.z = pack_bf16_rne(a4, a5);
  o.w = pack_bf16_rne(a6, a7);
  *(uint4*)(out + (size_t)bq * CDIM + h * 32 + dg * 8) = o;
}

extern "C" void kernel_launch(void* const* d_in, const int* in_sizes, int n_in,
                              void* d_out, int out_size, void* d_ws, size_t ws_size,
                              hipStream_t stream) {
  const float* query = (const float*)d_in[0];
  const float* refp = (const float*)d_in[1];
  const float* inflat = (const float*)d_in[2];
  const float* Wv = (const float*)d_in[3];
  const float* bv = (const float*)d_in[4];
  const float* Wof = (const float*)d_in[5];
  const float* bof = (const float*)d_in[6];
  const float* Wa = (const float*)d_in[7];
  const float* ba = (const float*)d_in[8];
  const float* Wo = (const float*)d_in[9];
  const float* bo = (const float*)d_in[10];
  float* out = (float*)d_out;

  const size_t M = MROWS;

  u16* ws_value = (u16*)d_ws;                    // M*256 bf16 row-major
  float* ws_off = (float*)(ws_value + M * 256);  // M*256 f32
  float* ws_attn = ws_off + M * 256;             // M*128 f32
  u16* ws_samp = (u16*)(ws_attn + M * 128);      // M*256 bf16
  u16* WfV = ws_samp + M * 256;                  // 256*256 bf16
  u16* WfC = WfV + 256 * 256;                    // 256*384 bf16
  u16* WfO = WfC + 384 * 256;                    // 256*256 bf16
  float* bcat = (float*)(WfO + 256 * 256);       // 384 f32

  conv_w<<<dim3(114), dim3(256), 0, stream>>>(Wv, Wof, Wa, Wo, bof, ba, WfV, WfC, WfO,
                                              bcat);
  gemm_v<<<dim3(680), dim3(256), 0, stream>>>(inflat, WfV, bv, ws_value);
  gemm_q<<<dim3(680), dim3(256), 0, stream>>>(query, WfC, bcat, ws_off, ws_attn);
  msda_sample3<<<dim3(5440), dim3(256), 0, stream>>>(ws_value, ws_off, ws_attn, refp,
                                                     ws_samp);
  gemm_out<<<dim3(680), dim3(256), 0, stream>>>(ws_samp, WfO, bo, out);
}

// Round 10
// 267.429 us; speedup vs baseline: 1.2683x; 1.0379x over previous
//
#include <hip/hip_runtime.h>

typedef unsigned short u16;
typedef unsigned int u32;
typedef short bf16x8 __attribute__((ext_vector_type(8)));
typedef float f32x4 __attribute__((ext_vector_type(4)));

#define LQ_ 21760
#define LIN_ 21760
#define CDIM 256
#define MROWS (2 * LQ_)  // 43520

__device__ __forceinline__ u16 f2bf(float f) {
  u32 u;
  __builtin_memcpy(&u, &f, 4);
  u32 r = (u + 0x7fffu + ((u >> 16) & 1u)) >> 16;
  return (u16)r;
}
__device__ __forceinline__ u32 pack_bf16_rne(float a, float b) {
  return (u32)f2bf(a) | ((u32)f2bf(b) << 16);
}
__device__ __forceinline__ float bflo(u32 u) {
  u32 v = u << 16;
  float f;
  __builtin_memcpy(&f, &v, 4);
  return f;
}
__device__ __forceinline__ float bfhi(u32 u) {
  u32 v = u & 0xffff0000u;
  float f;
  __builtin_memcpy(&f, &v, 4);
  return f;
}

// ---------- weight pre-conversion to bf16 fragment-chunk layout (B side) ----------
// chunkIdx = ks*(N/4) + (n>>4)*4 + ((k>>3)&3); element (n&15)*8 + (k&7).
__device__ __forceinline__ void conv_one(const float* W0, const float* W1, u16* Wf,
                                         int N, int split, int blk, int t) {
  const int tid = blk * 256 + t;
  if (tid >= N * 32) return;
  const int n = tid >> 5, kcg = tid & 31;
  float w[8];
#pragma unroll
  for (int j = 0; j < 8; ++j) {
    const int k = kcg * 8 + j;
    w[j] = (n < split) ? W0[(size_t)k * split + n]
                       : W1[(size_t)k * (N - split) + (n - split)];
  }
  uint4 pk;
  pk.x = pack_bf16_rne(w[0], w[1]);
  pk.y = pack_bf16_rne(w[2], w[3]);
  pk.z = pack_bf16_rne(w[4], w[5]);
  pk.w = pack_bf16_rne(w[6], w[7]);
  const int ks = kcg >> 2, kcr = kcg & 3, c = n >> 4;
  const int chunk = ks * (N / 4) + c * 4 + kcr;
  *(uint4*)(Wf + (size_t)chunk * 128 + (n & 15) * 8) = pk;
}

// ---------- weights-only pre-conversion ----------
__global__ __launch_bounds__(256) void conv_w(
    const float* __restrict__ Wv, const float* __restrict__ Wof,
    const float* __restrict__ Wa, const float* __restrict__ Wo,
    const float* __restrict__ bof, const float* __restrict__ ba,
    u16* __restrict__ WfV, u16* __restrict__ WfC, u16* __restrict__ WfO,
    float* __restrict__ bcat) {
  const int b = blockIdx.x, t = threadIdx.x;
  if (b < 32) {
    conv_one(Wv, Wv, WfV, 256, 256, b, t);
    return;
  }
  if (b < 80) {
    conv_one(Wof, Wa, WfC, 384, 256, b - 32, t);
    return;
  }
  if (b < 112) {
    conv_one(Wo, Wo, WfO, 256, 256, b - 80, t);
    return;
  }
  const int i = (b - 112) * 256 + t;
  if (i < 384) bcat[i] = (i < 256) ? bof[i] : ba[i - 256];
}

// ---------- LDS A-panel staging (64-row tiles, 32 KB) ----------
// LDS layout: 64 rows x 256 bf16, elem-col XOR-swizzled by ((row&7)<<3) in 8-elem
// (16 B) granules; staging ds_write and frag ds_read both conflict-free (measured 0).
__device__ __forceinline__ void stage_a_f32_64(u16* s_a, const float* __restrict__ ga,
                                               int t) {
#pragma unroll
  for (int it = 0; it < 8; ++it) {
    const int idx = it * 256 + t;
    const int row = idx >> 5, cc = idx & 31;
    const float4 f0 = *(const float4*)(ga + (size_t)row * 256 + cc * 8);
    const float4 f1 = *(const float4*)(ga + (size_t)row * 256 + cc * 8 + 4);
    uint4 pk;
    pk.x = pack_bf16_rne(f0.x, f0.y);
    pk.y = pack_bf16_rne(f0.z, f0.w);
    pk.z = pack_bf16_rne(f1.x, f1.y);
    pk.w = pack_bf16_rne(f1.z, f1.w);
    *(uint4*)(s_a + row * 256 + ((cc * 8) ^ ((row & 7) << 3))) = pk;
  }
}
__device__ __forceinline__ void stage_a_bf16_64(u16* s_a, const u16* __restrict__ ga,
                                                int t) {
#pragma unroll
  for (int it = 0; it < 8; ++it) {
    const int idx = it * 256 + t;
    const int row = idx >> 5, cc = idx & 31;
    const uint4 pk = *(const uint4*)(ga + (size_t)row * 256 + cc * 8);
    *(uint4*)(s_a + row * 256 + ((cc * 8) ^ ((row & 7) << 3))) = pk;
  }
}

// ---------- GEMM 1+2 (merged): 64-row tiles, A staged f32->bf16 in LDS ----------
// blocks [0,680): value = inflat @ WfV + bv (bf16 out, N=256, 2 cb)
// blocks [680,1360): [off|attn] = query @ WfC + bcat (BF16 out now, N=384, 3 cb)
__global__ __launch_bounds__(256, 4) void gemm_vq(
    const float* __restrict__ Ai, const u16* __restrict__ WfV,
    const float* __restrict__ bv, u16* __restrict__ outV,
    const float* __restrict__ Aq, const u16* __restrict__ WfC,
    const float* __restrict__ bcat, u16* __restrict__ outO,
    u16* __restrict__ outA) {
  __shared__ u16 s_a[64 * 256];  // 32 KB
  const int t = threadIdx.x, l = t & 63, wv = t >> 6;
  const int wr = wv >> 1, wc = wv & 1;
  const int fq = l >> 4, fr = l & 15;
  const int swz = (fr & 7) << 3;

  if (blockIdx.x < 680) {
    const int rb = blockIdx.x;
    stage_a_f32_64(s_a, Ai + (size_t)rb * 64 * 256, t);
    __syncthreads();
#pragma unroll
    for (int cb = 0; cb < 2; ++cb) {
      f32x4 acc[2][4];
#pragma unroll
      for (int r = 0; r < 2; ++r)
#pragma unroll
        for (int c = 0; c < 4; ++c) acc[r][c] = f32x4{0.f, 0.f, 0.f, 0.f};
      const u16* bb = WfV + ((size_t)(cb * 8 + wc * 4) * 4 + fq) * 128 + fr * 8;
#pragma unroll
      for (int ks = 0; ks < 8; ++ks) {
        bf16x8 af[2];
#pragma unroll
        for (int r = 0; r < 2; ++r) {
          const int row = wr * 32 + r * 16 + fr;
          af[r] = *(const bf16x8*)(s_a + row * 256 + ((ks * 32 + fq * 8) ^ swz));
        }
        bf16x8 bf[4];
#pragma unroll
        for (int c = 0; c < 4; ++c) bf[c] = *(const bf16x8*)(bb + ks * 8192 + c * 512);
#pragma unroll
        for (int c = 0; c < 4; ++c)
#pragma unroll
          for (int r = 0; r < 2; ++r)
            acc[r][c] = __builtin_amdgcn_mfma_f32_16x16x32_bf16(af[r], bf[c],
                                                                acc[r][c], 0, 0, 0);
      }
      const int rq = fq * 4;
#pragma unroll
      for (int c = 0; c < 4; ++c) {
        const int col = cb * 128 + wc * 64 + c * 16 + fr;
        const float bz = bv[col];
#pragma unroll
        for (int r = 0; r < 2; ++r) {
          const int row0 = rb * 64 + wr * 32 + r * 16 + rq;
#pragma unroll
          for (int g = 0; g < 4; ++g)
            outV[(size_t)(row0 + g) * 256 + col] = f2bf(acc[r][c][g] + bz);
        }
      }
    }
  } else {
    const int rb = blockIdx.x - 680;
    stage_a_f32_64(s_a, Aq + (size_t)rb * 64 * 256, t);
    __syncthreads();
#pragma unroll
    for (int cb = 0; cb < 3; ++cb) {
      f32x4 acc[2][4];
#pragma unroll
      for (int r = 0; r < 2; ++r)
#pragma unroll
        for (int c = 0; c < 4; ++c) acc[r][c] = f32x4{0.f, 0.f, 0.f, 0.f};
      const u16* bb = WfC + ((size_t)(cb * 8 + wc * 4) * 4 + fq) * 128 + fr * 8;
#pragma unroll
      for (int ks = 0; ks < 8; ++ks) {
        bf16x8 af[2];
#pragma unroll
        for (int r = 0; r < 2; ++r) {
          const int row = wr * 32 + r * 16 + fr;
          af[r] = *(const bf16x8*)(s_a + row * 256 + ((ks * 32 + fq * 8) ^ swz));
        }
        bf16x8 bf[4];
#pragma unroll
        for (int c = 0; c < 4; ++c) bf[c] = *(const bf16x8*)(bb + ks * 12288 + c * 512);
#pragma unroll
        for (int c = 0; c < 4; ++c)
#pragma unroll
          for (int r = 0; r < 2; ++r)
            acc[r][c] = __builtin_amdgcn_mfma_f32_16x16x32_bf16(af[r], bf[c],
                                                                acc[r][c], 0, 0, 0);
      }
      const int rq = fq * 4;
#pragma unroll
      for (int c = 0; c < 4; ++c) {
        const int col = cb * 128 + wc * 64 + c * 16 + fr;
        const float bz = bcat[col];
#pragma unroll
        for (int r = 0; r < 2; ++r) {
          const int row0 = rb * 64 + wr * 32 + r * 16 + rq;
#pragma unroll
          for (int g = 0; g < 4; ++g) {
            const float v = acc[r][c][g] + bz;
            if (col < 256)
              outO[(size_t)(row0 + g) * 256 + col] = f2bf(v);
            else
              outA[(size_t)(row0 + g) * 128 + (col - 256)] = f2bf(v);
          }
        }
      }
    }
  }
}

// ---------- GEMM 3: 64-row tiles, out = samp(bf16, LDS-staged) @ WfO + bo -> f32 ----
__global__ __launch_bounds__(256, 4) void gemm_out(
    const u16* __restrict__ A, const u16* __restrict__ Wf,
    const float* __restrict__ bias, float* __restrict__ out) {
  __shared__ u16 s_a[64 * 256];  // 32 KB
  const int rb = blockIdx.x;
  const int t = threadIdx.x, l = t & 63, wv = t >> 6;
  const int wr = wv >> 1, wc = wv & 1;
  const int fq = l >> 4, fr = l & 15;
  const int swz = (fr & 7) << 3;
  stage_a_bf16_64(s_a, A + (size_t)rb * 64 * 256, t);
  __syncthreads();
#pragma unroll
  for (int cb = 0; cb < 2; ++cb) {
    f32x4 acc[2][4];
#pragma unroll
    for (int r = 0; r < 2; ++r)
#pragma unroll
      for (int c = 0; c < 4; ++c) acc[r][c] = f32x4{0.f, 0.f, 0.f, 0.f};
    const u16* bb = Wf + ((size_t)(cb * 8 + wc * 4) * 4 + fq) * 128 + fr * 8;
#pragma unroll
    for (int ks = 0; ks < 8; ++ks) {
      bf16x8 af[2];
#pragma unroll
      for (int r = 0; r < 2; ++r) {
        const int row = wr * 32 + r * 16 + fr;
        af[r] = *(const bf16x8*)(s_a + row * 256 + ((ks * 32 + fq * 8) ^ swz));
      }
      bf16x8 bf[4];
#pragma unroll
      for (int c = 0; c < 4; ++c) bf[c] = *(const bf16x8*)(bb + ks * 8192 + c * 512);
#pragma unroll
      for (int c = 0; c < 4; ++c)
#pragma unroll
        for (int r = 0; r < 2; ++r)
          acc[r][c] = __builtin_amdgcn_mfma_f32_16x16x32_bf16(af[r], bf[c],
                                                              acc[r][c], 0, 0, 0);
    }
    const int rq = fq * 4;
#pragma unroll
    for (int c = 0; c < 4; ++c) {
      const int col = cb * 128 + wc * 64 + c * 16 + fr;
      const float bz = bias[col];
#pragma unroll
      for (int r = 0; r < 2; ++r) {
        const int row0 = rb * 64 + wr * 32 + r * 16 + rq;
#pragma unroll
        for (int g = 0; g < 4; ++g)
          out[(size_t)(row0 + g) * 256 + col] = acc[r][c][g] + bz;
      }
    }
  }
}

// ---------- sampler: proven structure; off/attn inputs now bf16 ----------
__global__ __launch_bounds__(256) void msda_sample3(
    const u16* __restrict__ value, const u16* __restrict__ off,
    const u16* __restrict__ attnl, const float* __restrict__ refp,
    u16* __restrict__ out) {
  __shared__ float s_aw[64 * 17];
  __shared__ uint4 s_idx[16 * 64];
  __shared__ float4 s_w[16 * 64];
  const int t = threadIdx.x;
  const int bq0 = blockIdx.x * 8;

  if (t < 64) {
    const u32* lg = (const u32*)(attnl + (size_t)(bq0 + (t >> 3)) * 128 + (t & 7) * 16);
    float e[16];
#pragma unroll
    for (int i = 0; i < 8; ++i) {
      const u32 u = lg[i];
      e[2 * i] = bflo(u);
      e[2 * i + 1] = bfhi(u);
    }
    float m = -1e30f;
#pragma unroll
    for (int i = 0; i < 16; ++i) m = fmaxf(m, e[i]);
    float s = 0.f;
#pragma unroll
    for (int i = 0; i < 16; ++i) {
      e[i] = __expf(e[i] - m);
      s += e[i];
    }
    const float inv = 1.f / s;
#pragma unroll
    for (int i = 0; i < 16; ++i) s_aw[t * 17 + i] = e[i] * inv;
  }
  __syncthreads();

#pragma unroll
  for (int rr = 0; rr < 4; ++rr) {
    const int id = t + rr * 256;
    const int qh = id & 63, lp = id >> 6;
    const int q = qh >> 3, h = qh & 7, lv = lp >> 2, p = lp & 3;
    const int bq = bq0 + q;
    const int Wl = 128 >> lv;
    const int st = (lv == 0) ? 0 : (lv == 1) ? 16384 : (lv == 2) ? 20480 : 21504;
    const u32 o2 = *(const u32*)(off + (size_t)bq * 256 + ((h * 4 + lv) * 4 + p) * 2);
    const float ox = bflo(o2);
    const float oy = bfhi(o2);
    const float rx = refp[(size_t)bq * 8 + lv * 2];
    const float ry = refp[(size_t)bq * 8 + lv * 2 + 1];
    const float aw = s_aw[qh * 17 + lp];
    const float x = rx * (float)Wl + ox - 0.5f;
    const float y = ry * (float)Wl + oy - 0.5f;
    const float xf = floorf(x), yf = floorf(y);
    const int x0 = (int)xf, y0 = (int)yf;
    const float lw = x - xf, lh = y - yf;
    const float hw = 1.f - lw, hh = 1.f - lh;
    const int ixs[4] = {x0, x0 + 1, x0, x0 + 1};
    const int iys[4] = {y0, y0, y0 + 1, y0 + 1};
    const float wts[4] = {hw * hh, lw * hh, hw * lh, lw * lh};
    u32 rows[4];
    float ws4[4];
#pragma unroll
    for (int c = 0; c < 4; ++c) {
      const int ix = ixs[c], iy = iys[c];
      const bool valid = (ix >= 0) & (ix < Wl) & (iy >= 0) & (iy < Wl);
      int idx = iy * Wl + ix;
      idx = max(0, min(idx, Wl * Wl - 1));
      rows[c] = (u32)(st + idx);
      ws4[c] = valid ? (wts[c] * aw) : 0.f;
    }
    uint4 iv;
    iv.x = rows[0];
    iv.y = rows[1];
    iv.z = rows[2];
    iv.w = rows[3];
    s_idx[lp * 64 + qh] = iv;
    s_w[lp * 64 + qh] = make_float4(ws4[0], ws4[1], ws4[2], ws4[3]);
  }
  __syncthreads();

  const int q = t >> 5, h = (t >> 2) & 7, dg = t & 3;
  const int qh = q * 8 + h;
  const int bq = bq0 + q;
  const u16* vp = value + (size_t)((bq >= LQ_) ? LIN_ : 0) * CDIM + h * 32 + dg * 8;
  float a0 = 0.f, a1 = 0.f, a2 = 0.f, a3 = 0.f;
  float a4 = 0.f, a5 = 0.f, a6 = 0.f, a7 = 0.f;
#pragma unroll 4
  for (int lp = 0; lp < 16; ++lp) {
    const uint4 iv = s_idx[lp * 64 + qh];
    const float4 wv = s_w[lp * 64 + qh];
    const u32 rows[4] = {iv.x, iv.y, iv.z, iv.w};
    const float ww[4] = {wv.x, wv.y, wv.z, wv.w};
#pragma unroll
    for (int c = 0; c < 4; ++c) {
      const uint4 d = *(const uint4*)(vp + (size_t)rows[c] * CDIM);
      const float w = ww[c];
      a0 += w * bflo(d.x);
      a1 += w * bfhi(d.x);
      a2 += w * bflo(d.y);
      a3 += w * bfhi(d.y);
      a4 += w * bflo(d.z);
      a5 += w * bfhi(d.z);
      a6 += w * bflo(d.w);
      a7 += w * bfhi(d.w);
    }
  }
  uint4 o;
  o.x = pack_bf16_rne(a0, a1);
  o.y = pack_bf16_rne(a2, a3);
  o.z = pack_bf16_rne(a4, a5);
  o.w = pack_bf16_rne(a6, a7);
  *(uint4*)(out + (size_t)bq * CDIM + h * 32 + dg * 8) = o;
}

extern "C" void kernel_launch(void* const* d_in, const int* in_sizes, int n_in,
                              void* d_out, int out_size, void* d_ws, size_t ws_size,
                              hipStream_t stream) {
  const float* query = (const float*)d_in[0];
  const float* refp = (const float*)d_in[1];
  const float* inflat = (const float*)d_in[2];
  const float* Wv = (const float*)d_in[3];
  const float* bv = (const float*)d_in[4];
  const float* Wof = (const float*)d_in[5];
  const float* bof = (const float*)d_in[6];
  const float* Wa = (const float*)d_in[7];
  const float* ba = (const float*)d_in[8];
  const float* Wo = (const float*)d_in[9];
  const float* bo = (const float*)d_in[10];
  float* out = (float*)d_out;

  const size_t M = MROWS;

  u16* ws_value = (u16*)d_ws;       // M*256 bf16 row-major
  u16* ws_off = ws_value + M * 256;  // M*256 bf16 (was f32)
  u16* ws_attn = ws_off + M * 256;   // M*128 bf16 (was f32)
  u16* ws_samp = ws_attn + M * 128;  // M*256 bf16
  u16* WfV = ws_samp + M * 256;      // 256*256 bf16
  u16* WfC = WfV + 256 * 256;        // 256*384 bf16
  u16* WfO = WfC + 384 * 256;        // 256*256 bf16
  float* bcat = (float*)(WfO + 256 * 256);  // 384 f32

  conv_w<<<dim3(114), dim3(256), 0, stream>>>(Wv, Wof, Wa, Wo, bof, ba, WfV, WfC, WfO,
                                              bcat);
  gemm_vq<<<dim3(1360), dim3(256), 0, stream>>>(inflat, WfV, bv, ws_value, query, WfC,
                                                bcat, ws_off, ws_attn);
  msda_sample3<<<dim3(5440), dim3(256), 0, stream>>>(ws_value, ws_off, ws_attn, refp,
                                                     ws_samp);
  gemm_out<<<dim3(680), dim3(256), 0, stream>>>(ws_samp, WfO, bo, out);
}